// Round 8
// baseline (825.535 us; speedup 1.0000x reference)
//
#include <hip/hip_runtime.h>

// B=16, LQ=LP=2048, H=1024
//   q_lin = relu(q @ W^T + b); p_lin = relu(p @ W^T + b)
//   scores = p_lin @ q_lin^T ; att = softmax(scores); out = att @ q_lin
// GEMMs: 256x256 tile, BK=64, 8 waves, 8-phase schedule, fp16 MFMA 16x16x32.
// Round-8: ONE-PHASE-AHEAD fragment pipeline — phase p's MFMA consumes frags
// ds_read in phase p-1 (two A-sets, two B-sets); vmcnt(4) at P3/P7 so each
// buffer is staged one phase before its first frag load. No lgkmcnt drains.

#define LQN 2048
#define LPN 2048
#define HD  1024
#define NBATCH 16

typedef _Float16 half8 __attribute__((ext_vector_type(8)));
typedef _Float16 half4_t __attribute__((ext_vector_type(4)));
typedef float f32x4 __attribute__((ext_vector_type(4)));

#define GLP(src, dst) __builtin_amdgcn_global_load_lds(                          \
    (const __attribute__((address_space(1))) void*)(src),                        \
    (__attribute__((address_space(3))) void*)(dst), 16, 0, 0)

// ---------------------------------------------------------------- convert f32->f16
__global__ __launch_bounds__(256) void cvt_f32_f16(const float* __restrict__ in,
                                                   _Float16* __restrict__ out,
                                                   long n4) {
  long i0 = (long)blockIdx.x * blockDim.x + threadIdx.x;
  long stride = (long)gridDim.x * blockDim.x;
  for (long i = i0; i < n4; i += stride) {
    float4 v = ((const float4*)in)[i];
    half4_t h = {(_Float16)v.x, (_Float16)v.y, (_Float16)v.z, (_Float16)v.w};
    ((half4_t*)out)[i] = h;
  }
}

// ---------------------------------------------------------------- 8-phase 256^2 GEMM
// EPI 0: f32 C (+z*sCz).  EPI 1: fp16 C = relu(acc+bias) + fp16 CT for q rows.
// EPI 2: fp16 P_t = exp(s - m_t) per 256-col tile + side (m_t, sum_t).

#define SYNC_PRE                                        \
  __builtin_amdgcn_sched_barrier(0);                    \
  __builtin_amdgcn_s_barrier();                         \
  __builtin_amdgcn_s_setprio(1);

#define SYNC_POST                                       \
  __builtin_amdgcn_s_setprio(0);                        \
  __builtin_amdgcn_s_barrier();                         \
  __builtin_amdgcn_sched_barrier(0);

#define SYNC_POST_VM                                    \
  __builtin_amdgcn_s_setprio(0);                        \
  asm volatile("s_waitcnt vmcnt(4)" ::: "memory");      \
  __builtin_amdgcn_s_barrier();                         \
  __builtin_amdgcn_sched_barrier(0);

#define LOADA_TO(dst, qm, buf)                                                    \
  _Pragma("unroll")                                                               \
  for (int mi = 0; mi < 4; ++mi) {                                                \
    dst[mi][0] = *(const half8*)(smA + (buf)*32768 + a0 + ((qm)*4+mi)*4096);      \
    dst[mi][1] = *(const half8*)(smA + (buf)*32768 + a1 + ((qm)*4+mi)*4096);      \
  }

#define LOADB_TO(dst, qn, buf)                                                    \
  _Pragma("unroll")                                                               \
  for (int ni = 0; ni < 2; ++ni) {                                                \
    dst[ni][0] = *(const half8*)(smB + (buf)*32768 + b0 + ((qn)*2+ni)*8192);      \
    dst[ni][1] = *(const half8*)(smB + (buf)*32768 + b1 + ((qn)*2+ni)*8192);      \
  }

#define STAGEA(t, h, buf) do {                                                    \
  GLP(gA + (size_t)((h)*128)*lda + (size_t)(t)*64,                                \
      smW + (buf)*32768 + (h)*16384 + wid*1024);                                  \
  GLP(gA + (size_t)((h)*128+64)*lda + (size_t)(t)*64,                             \
      smW + (buf)*32768 + (h)*16384 + 8192 + wid*1024);                           \
} while (0)

#define STAGEB(t, h, buf) do {                                                    \
  GLP(gB + (size_t)((h)*128)*ldb + (size_t)(t)*64,                                \
      smW + 65536 + (buf)*32768 + (h)*16384 + wid*1024);                          \
  GLP(gB + (size_t)((h)*128+64)*ldb + (size_t)(t)*64,                             \
      smW + 65536 + (buf)*32768 + (h)*16384 + 8192 + wid*1024);                   \
} while (0)

#define DO_MFMA2(aset, bset, qm, qn)                                              \
  _Pragma("unroll")                                                               \
  for (int mi = 0; mi < 4; ++mi) {                                                \
    _Pragma("unroll")                                                             \
    for (int ni = 0; ni < 2; ++ni) {                                              \
      acc[(qm)*4+mi][(qn)*2+ni] = __builtin_amdgcn_mfma_f32_16x16x32_f16(         \
          aset[mi][0], bset[ni][0], acc[(qm)*4+mi][(qn)*2+ni], 0, 0, 0);          \
      acc[(qm)*4+mi][(qn)*2+ni] = __builtin_amdgcn_mfma_f32_16x16x32_f16(         \
          aset[mi][1], bset[ni][1], acc[(qm)*4+mi][(qn)*2+ni], 0, 0, 0);          \
    }                                                                             \
  }

template <int EPI>
__global__ __launch_bounds__(512, 2) void gemm8p(
    const _Float16* __restrict__ A, const _Float16* __restrict__ B,
    const float* __restrict__ bias, void* __restrict__ Cv,
    _Float16* __restrict__ CT, float2* __restrict__ side,
    int K, int lda, int ldb, int ldc, long sAz, long sBz, long sCz) {
  extern __shared__ __align__(16) char smem[];
  const char* smA = smem;
  const char* smB = smem + 65536;
  char* smW = smem;

  const int tid = threadIdx.x;
  const int lane = tid & 63, wid = tid >> 6;
  const int l16 = lane & 15, lhi = lane >> 4;
  const int wr = wid >> 2, wcn = wid & 3;

  // N-fast + XCD-chunked mapping
  const int nx = gridDim.x;
  const int d = blockIdx.y * nx + blockIdx.x;
  const int cpx = (nx * gridDim.y) >> 3;
  const int t_ = (d & 7) * cpx + (d >> 3);
  const int xsh = 31 - __builtin_clz(nx);
  const int bn0 = (t_ & (nx - 1)) << 8;
  const int bm0 = (t_ >> xsh) << 8;

  // swizzle: flip 16B-slot bits 4-6 by row bits 0-2
  const int mask = (l16 & 7) << 4;
  const int a0 = (wr * 2048 + l16 * 128 + lhi * 16) ^ mask;
  const int a1 = a0 ^ 64;
  const int b0 = (wcn * 2048 + l16 * 128 + lhi * 16) ^ mask;
  const int b1 = b0 ^ 64;

  const int srow = tid >> 3;
  const int scol = (((tid & 7) ^ ((tid >> 3) & 7)) << 3);

  const _Float16* gA = A + (size_t)blockIdx.z * sAz + (size_t)(bm0 + srow) * lda + scol;
  const _Float16* gB = B + (size_t)blockIdx.z * sBz + (size_t)(bn0 + srow) * ldb + scol;

  const int NT = K >> 6, NI = K >> 7;

  f32x4 acc[8][4] = {};
  half8 aA0[4][2], aA1[4][2], bs0[2][2], bs1[2][2];

  // prologue: tile0 (4 halves, buf0) + tile1 (Ah0,Ah1,Bh0 -> buf1)
  STAGEA(0, 0, 0); STAGEA(0, 1, 0); STAGEB(0, 0, 0); STAGEB(0, 1, 0);
  STAGEA(1, 0, 1); STAGEA(1, 1, 1); STAGEB(1, 0, 1);
  __builtin_amdgcn_sched_barrier(0);
  asm volatile("s_waitcnt vmcnt(6)" ::: "memory");
  __builtin_amdgcn_s_barrier();
  __builtin_amdgcn_sched_barrier(0);
  LOADA_TO(aA0, 0, 0) LOADB_TO(bs0, 0, 0)

  for (int i = 0; i < NI; ++i) {
    int t2c = 2 * i + 2; if (t2c > NT - 1) t2c = NT - 1;
    int t3c = 2 * i + 3; if (t3c > NT - 1) t3c = NT - 1;
    // P1: compute (0,0) of tile 2i [buf0]; load A1,B1 of 2i; stage B(2i+1,h1)
    STAGEB(2 * i + 1, 1, 1); LOADB_TO(bs1, 1, 0) LOADA_TO(aA1, 1, 0)
    SYNC_PRE DO_MFMA2(aA0, bs0, 0, 0) SYNC_POST
    // P2: compute (0,1); stage A(t+2,h0)->buf0
    STAGEA(t2c, 0, 0);
    SYNC_PRE DO_MFMA2(aA0, bs1, 0, 1) SYNC_POST
    // P3: compute (1,0); stage A(t+2,h1)->buf0 ; vmcnt(4): tile 2i+1 ready
    STAGEA(t2c, 1, 0);
    SYNC_PRE DO_MFMA2(aA1, bs0, 1, 0) SYNC_POST_VM
    // P4: compute (1,1); load A0,B0 of 2i+1 [buf1]; stage B(t+2,h0)->buf0
    STAGEB(t2c, 0, 0); LOADA_TO(aA0, 0, 1) LOADB_TO(bs0, 0, 1)
    SYNC_PRE DO_MFMA2(aA1, bs1, 1, 1) SYNC_POST
    // P5: compute (0,0) of tile 2i+1; load A1,B1 of 2i+1; stage B(t+2,h1)->buf0
    STAGEB(t2c, 1, 0); LOADB_TO(bs1, 1, 1) LOADA_TO(aA1, 1, 1)
    SYNC_PRE DO_MFMA2(aA0, bs0, 0, 0) SYNC_POST
    // P6: compute (0,1); stage A(t+3,h0)->buf1
    STAGEA(t3c, 0, 1);
    SYNC_PRE DO_MFMA2(aA0, bs1, 0, 1) SYNC_POST
    // P7: compute (1,0); stage A(t+3,h1)->buf1 ; vmcnt(4): tile 2i+2 ready
    STAGEA(t3c, 1, 1);
    SYNC_PRE DO_MFMA2(aA1, bs0, 1, 0) SYNC_POST_VM
    // P8: compute (1,1); load A0,B0 of 2i+2 [buf0]; stage B(t+3,h0)->buf1
    STAGEB(t3c, 0, 1); LOADA_TO(aA0, 0, 0) LOADB_TO(bs0, 0, 0)
    SYNC_PRE DO_MFMA2(aA1, bs1, 1, 1) SYNC_POST
  }

  if constexpr (EPI == 0) {
    float* Cb = (float*)Cv + (size_t)blockIdx.z * sCz;
#pragma unroll
    for (int m = 0; m < 8; ++m) {
      int row0 = bm0 + m * 32 + wr * 16 + lhi * 4;
#pragma unroll
      for (int n = 0; n < 4; ++n) {
        int col = bn0 + n * 64 + wcn * 16 + l16;
#pragma unroll
        for (int v = 0; v < 4; ++v)
          Cb[(size_t)(row0 + v) * ldc + col] = acc[m][n][v];
      }
    }
  } else if constexpr (EPI == 1) {
    _Float16* Cb = (_Float16*)Cv;
    const bool doCT = (bm0 < NBATCH * LQN);
#pragma unroll
    for (int n = 0; n < 4; ++n) {
      int col = bn0 + n * 64 + wcn * 16 + l16;
      float bv = bias[col];
#pragma unroll
      for (int m = 0; m < 8; ++m) {
        int row0 = bm0 + m * 32 + wr * 16 + lhi * 4;
        float v0 = fmaxf(acc[m][n][0] + bv, 0.f);
        float v1 = fmaxf(acc[m][n][1] + bv, 0.f);
        float v2 = fmaxf(acc[m][n][2] + bv, 0.f);
        float v3 = fmaxf(acc[m][n][3] + bv, 0.f);
        Cb[(size_t)(row0 + 0) * ldc + col] = (_Float16)v0;
        Cb[(size_t)(row0 + 1) * ldc + col] = (_Float16)v1;
        Cb[(size_t)(row0 + 2) * ldc + col] = (_Float16)v2;
        Cb[(size_t)(row0 + 3) * ldc + col] = (_Float16)v3;
        if (doCT) {
          half4_t h = {(_Float16)v0, (_Float16)v1, (_Float16)v2, (_Float16)v3};
          int bz = row0 >> 11, qi = row0 & 2047;
          *(half4_t*)&CT[(size_t)bz * ((size_t)HD * LQN) + (size_t)col * LQN + qi] = h;
        }
      }
    }
  } else {
    // EPI == 2: partial softmax over this block's 256 cols.
    // redm/reds in smem[0,8KB) = buf0-A; outstanding GLPs at exit target buf1
    // only (P6,P7,P8); __syncthreads() drains counters anyway.
    float* redm = (float*)smW;            // [256][4]
    float* reds = (float*)(smW + 4096);   // [256][4]
    float tm[8][4];
#pragma unroll
    for (int m = 0; m < 8; ++m)
#pragma unroll
      for (int v = 0; v < 4; ++v)
        tm[m][v] = fmaxf(fmaxf(acc[m][0][v], acc[m][1][v]),
                         fmaxf(acc[m][2][v], acc[m][3][v]));
#pragma unroll
    for (int o = 1; o < 16; o <<= 1)
#pragma unroll
      for (int m = 0; m < 8; ++m)
#pragma unroll
        for (int v = 0; v < 4; ++v)
          tm[m][v] = fmaxf(tm[m][v], __shfl_xor(tm[m][v], o));
    __syncthreads();
    if (l16 == 0) {
#pragma unroll
      for (int m = 0; m < 8; ++m)
#pragma unroll
        for (int v = 0; v < 4; ++v)
          redm[(m * 32 + wr * 16 + lhi * 4 + v) * 4 + wcn] = tm[m][v];
    }
    __syncthreads();
    float rm[8][4], rs[8][4];
#pragma unroll
    for (int m = 0; m < 8; ++m)
#pragma unroll
      for (int v = 0; v < 4; ++v) {
        float4 q4 = ((const float4*)redm)[m * 32 + wr * 16 + lhi * 4 + v];
        rm[m][v] = fmaxf(fmaxf(q4.x, q4.y), fmaxf(q4.z, q4.w));
      }
#pragma unroll
    for (int m = 0; m < 8; ++m)
#pragma unroll
      for (int v = 0; v < 4; ++v) {
        float s = 0.f;
#pragma unroll
        for (int n = 0; n < 4; ++n) {
          float e = __expf(acc[m][n][v] - rm[m][v]);
          acc[m][n][v] = e;
          s += e;
        }
        tm[m][v] = s;
      }
#pragma unroll
    for (int o = 1; o < 16; o <<= 1)
#pragma unroll
      for (int m = 0; m < 8; ++m)
#pragma unroll
        for (int v = 0; v < 4; ++v)
          tm[m][v] += __shfl_xor(tm[m][v], o);
    __syncthreads();
    if (l16 == 0) {
#pragma unroll
      for (int m = 0; m < 8; ++m)
#pragma unroll
        for (int v = 0; v < 4; ++v)
          reds[(m * 32 + wr * 16 + lhi * 4 + v) * 4 + wcn] = tm[m][v];
    }
    __syncthreads();
#pragma unroll
    for (int m = 0; m < 8; ++m)
#pragma unroll
      for (int v = 0; v < 4; ++v) {
        float4 q4 = ((const float4*)reds)[m * 32 + wr * 16 + lhi * 4 + v];
        rs[m][v] = (q4.x + q4.y) + (q4.z + q4.w);
      }
    _Float16* Cb = (_Float16*)Cv + (size_t)blockIdx.z * sCz;
#pragma unroll
    for (int n = 0; n < 4; ++n) {
      int col = bn0 + n * 64 + wcn * 16 + l16;
#pragma unroll
      for (int m = 0; m < 8; ++m) {
        int row0 = bm0 + m * 32 + wr * 16 + lhi * 4;
        Cb[(size_t)(row0 + 0) * ldc + col] = (_Float16)acc[m][n][0];
        Cb[(size_t)(row0 + 1) * ldc + col] = (_Float16)acc[m][n][1];
        Cb[(size_t)(row0 + 2) * ldc + col] = (_Float16)acc[m][n][2];
        Cb[(size_t)(row0 + 3) * ldc + col] = (_Float16)acc[m][n][3];
      }
    }
    if (l16 == 0 && wcn == 0) {
      float2* sb = side + ((size_t)blockIdx.z * 2048 + bm0) * 8 + (bn0 >> 8);
#pragma unroll
      for (int m = 0; m < 8; ++m)
#pragma unroll
        for (int v = 0; v < 4; ++v) {
          int r = m * 32 + wr * 16 + lhi * 4 + v;
          sb[(size_t)r * 8] = make_float2(rm[m][v], rs[m][v]);
        }
    }
  }
}

// ---------------------------------------------------------------- global renorm
__global__ __launch_bounds__(256) void renorm_k(_Float16* __restrict__ P,
                                                const float2* __restrict__ side) {
  const int row = blockIdx.x;
  const int bz = blockIdx.y;
  const float2* sd = side + ((size_t)bz * 2048 + row) * 8;
  float mt[8], st[8];
#pragma unroll
  for (int t = 0; t < 8; ++t) { float2 v = sd[t]; mt[t] = v.x; st[t] = v.y; }
  float m = mt[0];
#pragma unroll
  for (int t = 1; t < 8; ++t) m = fmaxf(m, mt[t]);
  float S = 0.f;
#pragma unroll
  for (int t = 0; t < 8; ++t) S += st[t] * __expf(mt[t] - m);
  const float inv = 1.f / S;
  const int tid = threadIdx.x;
  const float sc = __expf(mt[tid >> 5] - m) * inv;
  _Float16* p = P + (((size_t)bz * 2048 + row) * 2048) + tid * 8;
  half8 v = *(half8*)p;
#pragma unroll
  for (int j = 0; j < 8; ++j) v[j] = (_Float16)((float)v[j] * sc);
  *(half8*)p = v;
}

// ---------------------------------------------------------------- launch
extern "C" void kernel_launch(void* const* d_in, const int* in_sizes, int n_in,
                              void* d_out, int out_size, void* d_ws, size_t ws_size,
                              hipStream_t stream) {
  const float* q = (const float*)d_in[0];
  const float* p = (const float*)d_in[1];
  const float* W = (const float*)d_in[2];
  const float* bias = (const float*)d_in[3];
  float* out = (float*)d_out;
  char* ws = (char*)d_ws;

  _Float16* qf    = (_Float16*)(ws);
  _Float16* pf    = (_Float16*)(ws + 67108864L);
  _Float16* qlin  = (_Float16*)(ws + 134217728L);
  _Float16* plin  = (_Float16*)(ws + 201326592L);
  _Float16* qlinT = (_Float16*)(ws + 268435456L);
  _Float16* Wf    = (_Float16*)(ws + 335544320L);
  _Float16* Pbuf  = (_Float16*)(ws);
  float2*   side  = (float2*)(ws + 67108864L);

  const long nQ = (long)NBATCH * LQN * HD;
  const size_t SH = 131072;

  cvt_f32_f16<<<2048, 256, 0, stream>>>(q, qf, nQ / 4);
  cvt_f32_f16<<<2048, 256, 0, stream>>>(p, pf, nQ / 4);
  cvt_f32_f16<<<64, 256, 0, stream>>>(W, Wf, (long)HD * HD / 4);

  // fused shared linear + relu over q|p (M=65536); CT (q_linT) for q rows
  gemm8p<1><<<dim3(HD / 256, 2 * NBATCH * LQN / 256, 1), 512, SH, stream>>>(
      qf, Wf, bias, qlin, qlinT, (float2*)0, HD, HD, HD, HD, 0, 0, 0);

  for (int c = 0; c < 2; ++c) {
    int bz0 = c * 8;
    gemm8p<2><<<dim3(LQN / 256, LPN / 256, 8), 512, SH, stream>>>(
        plin + (size_t)bz0 * LPN * HD, qlin + (size_t)bz0 * LQN * HD,
        (const float*)0, Pbuf, (_Float16*)0, side,
        /*K=*/HD, /*lda=*/HD, /*ldb=*/HD, /*ldc=*/LQN,
        (long)LPN * HD, (long)LQN * HD, (long)LPN * LQN);
    renorm_k<<<dim3(LPN, 8), 256, 0, stream>>>(Pbuf, side);
    gemm8p<0><<<dim3(HD / 256, LPN / 256, 8), 512, SH, stream>>>(
        Pbuf, qlinT + (size_t)bz0 * HD * LQN,
        (const float*)0, out + (size_t)bz0 * LPN * HD, (_Float16*)0, (float2*)0,
        /*K=*/LQN, /*lda=*/LQN, /*ldb=*/LQN, /*ldc=*/HD,
        (long)LPN * LQN, (long)HD * LQN, (long)LPN * HD);
  }
}

// Round 9
// 593.131 us; speedup vs baseline: 1.3918x; 1.3918x over previous
//
#include <hip/hip_runtime.h>

// B=16, LQ=LP=2048, H=1024
//   q_lin = relu(q @ W^T + b); p_lin = relu(p @ W^T + b)
//   scores = p_lin @ q_lin^T ; att = softmax(scores); out = att @ q_lin
// GEMMs: 256x256 tile, BK=64, 8 waves, fp16 MFMA 16x16x32.
// Round-9: 4-phase/2-tile schedule (2 phases per K-tile, 32 MFMA/phase).
// Stage pattern: Qa(t) tops stage h1s of tile t+1 (other buf); Qb(t) tops
// stage h0s of tile t+2 (same buf); vmcnt(4) at each Qb end. r8's pipeline
// and CT-epilogue both reverted (confirmed regressions).

#define LQN 2048
#define LPN 2048
#define HD  1024
#define NBATCH 16

typedef _Float16 half8 __attribute__((ext_vector_type(8)));
typedef _Float16 half4_t __attribute__((ext_vector_type(4)));
typedef float f32x4 __attribute__((ext_vector_type(4)));

#define GLP(src, dst) __builtin_amdgcn_global_load_lds(                          \
    (const __attribute__((address_space(1))) void*)(src),                        \
    (__attribute__((address_space(3))) void*)(dst), 16, 0, 0)

// ---------------------------------------------------------------- convert f32->f16
__global__ __launch_bounds__(256) void cvt_f32_f16(const float* __restrict__ in,
                                                   _Float16* __restrict__ out,
                                                   long n4) {
  long i0 = (long)blockIdx.x * blockDim.x + threadIdx.x;
  long stride = (long)gridDim.x * blockDim.x;
  for (long i = i0; i < n4; i += stride) {
    float4 v = ((const float4*)in)[i];
    half4_t h = {(_Float16)v.x, (_Float16)v.y, (_Float16)v.z, (_Float16)v.w};
    ((half4_t*)out)[i] = h;
  }
}

// ---------------------------------------------------------------- tiled transpose
__global__ __launch_bounds__(256) void transpose_k(const _Float16* __restrict__ in,
                                                   _Float16* __restrict__ out) {
  __shared__ _Float16 t[64][72];
  const int bz = blockIdx.z;
  const int q0 = blockIdx.x * 64;
  const int d0 = blockIdx.y * 64;
  const int tt = threadIdx.x;
  const int ql = tt & 63, dg = tt >> 6;
  const _Float16* src = in + ((size_t)bz * LQN + q0 + ql) * HD + d0 + dg * 16;
  half8 v0 = *(const half8*)(src);
  half8 v1 = *(const half8*)(src + 8);
  int g0 = (dg * 2) ^ (ql & 7);
  int g1 = (dg * 2 + 1) ^ (ql & 7);
  *(half8*)&t[ql][g0 * 8] = v0;
  *(half8*)&t[ql][g1 * 8] = v1;
  __syncthreads();
  const int dl = tt & 63, qg = tt >> 6;
  half8 o0, o1;
#pragma unroll
  for (int j = 0; j < 8; ++j) {
    int qq = qg * 16 + j;
    o0[j] = t[qq][(((dl >> 3) ^ (qq & 7)) << 3) + (dl & 7)];
  }
#pragma unroll
  for (int j = 0; j < 8; ++j) {
    int qq = qg * 16 + 8 + j;
    o1[j] = t[qq][(((dl >> 3) ^ (qq & 7)) << 3) + (dl & 7)];
  }
  _Float16* dst = out + ((size_t)bz * HD + d0 + dl) * LQN + q0 + qg * 16;
  *(half8*)dst = o0;
  *(half8*)(dst + 8) = o1;
}

// ---------------------------------------------------------------- 4-phase 256^2 GEMM
// EPI 0: f32 C (+z*sCz).  EPI 1: fp16 C = relu(acc+bias).
// EPI 2: fp16 P_t = exp(s - m_t) per 256-col tile + side (m_t, sum_t).

#define SYNC_PRE                                        \
  __builtin_amdgcn_s_barrier();                         \
  __builtin_amdgcn_s_setprio(1);

#define SYNC_POST                                       \
  __builtin_amdgcn_s_setprio(0);                        \
  __builtin_amdgcn_s_barrier();                         \
  __builtin_amdgcn_sched_barrier(0);

#define SYNC_POST_VM                                    \
  __builtin_amdgcn_s_setprio(0);                        \
  asm volatile("s_waitcnt vmcnt(4)" ::: "memory");      \
  __builtin_amdgcn_s_barrier();                         \
  __builtin_amdgcn_sched_barrier(0);

#define LOADA_TO(dst, qm, buf)                                                    \
  _Pragma("unroll")                                                               \
  for (int mi = 0; mi < 4; ++mi) {                                                \
    dst[mi][0] = *(const half8*)(smA + (buf)*32768 + a0 + ((qm)*4+mi)*4096);      \
    dst[mi][1] = *(const half8*)(smA + (buf)*32768 + a1 + ((qm)*4+mi)*4096);      \
  }

#define LOADB_TO(dst, qn, buf)                                                    \
  _Pragma("unroll")                                                               \
  for (int ni = 0; ni < 2; ++ni) {                                                \
    dst[ni][0] = *(const half8*)(smB + (buf)*32768 + b0 + ((qn)*2+ni)*8192);      \
    dst[ni][1] = *(const half8*)(smB + (buf)*32768 + b1 + ((qn)*2+ni)*8192);      \
  }

#define STAGEA(t, h, buf) do {                                                    \
  GLP(gA + (size_t)((h)*128)*lda + (size_t)(t)*64,                                \
      smW + (buf)*32768 + (h)*16384 + wid*1024);                                  \
  GLP(gA + (size_t)((h)*128+64)*lda + (size_t)(t)*64,                             \
      smW + (buf)*32768 + (h)*16384 + 8192 + wid*1024);                           \
} while (0)

#define STAGEB(t, h, buf) do {                                                    \
  GLP(gB + (size_t)((h)*128)*ldb + (size_t)(t)*64,                                \
      smW + 65536 + (buf)*32768 + (h)*16384 + wid*1024);                          \
  GLP(gB + (size_t)((h)*128+64)*ldb + (size_t)(t)*64,                             \
      smW + 65536 + (buf)*32768 + (h)*16384 + 8192 + wid*1024);                   \
} while (0)

#define DO_MFMA2(aset, bset, qm, qn)                                              \
  _Pragma("unroll")                                                               \
  for (int mi = 0; mi < 4; ++mi) {                                                \
    _Pragma("unroll")                                                             \
    for (int ni = 0; ni < 2; ++ni) {                                              \
      acc[(qm)*4+mi][(qn)*2+ni] = __builtin_amdgcn_mfma_f32_16x16x32_f16(         \
          aset[mi][0], bset[ni][0], acc[(qm)*4+mi][(qn)*2+ni], 0, 0, 0);          \
      acc[(qm)*4+mi][(qn)*2+ni] = __builtin_amdgcn_mfma_f32_16x16x32_f16(         \
          aset[mi][1], bset[ni][1], acc[(qm)*4+mi][(qn)*2+ni], 0, 0, 0);          \
    }                                                                             \
  }

template <int EPI>
__global__ __launch_bounds__(512, 2) void gemm8p(
    const _Float16* __restrict__ A, const _Float16* __restrict__ B,
    const float* __restrict__ bias, void* __restrict__ Cv,
    float2* __restrict__ side, int K, int lda, int ldb, int ldc,
    long sAz, long sBz, long sCz) {
  extern __shared__ __align__(16) char smem[];
  const char* smA = smem;
  const char* smB = smem + 65536;
  char* smW = smem;

  const int tid = threadIdx.x;
  const int lane = tid & 63, wid = tid >> 6;
  const int l16 = lane & 15, lhi = lane >> 4;
  const int wr = wid >> 2, wcn = wid & 3;

  // N-fast + XCD-chunked mapping
  const int nx = gridDim.x;
  const int d = blockIdx.y * nx + blockIdx.x;
  const int cpx = (nx * gridDim.y) >> 3;
  const int t_ = (d & 7) * cpx + (d >> 3);
  const int xsh = 31 - __builtin_clz(nx);
  const int bn0 = (t_ & (nx - 1)) << 8;
  const int bm0 = (t_ >> xsh) << 8;

  // swizzle: flip 16B-slot bits 4-6 by row bits 0-2
  const int mask = (l16 & 7) << 4;
  const int a0 = (wr * 2048 + l16 * 128 + lhi * 16) ^ mask;
  const int a1 = a0 ^ 64;
  const int b0 = (wcn * 2048 + l16 * 128 + lhi * 16) ^ mask;
  const int b1 = b0 ^ 64;

  const int srow = tid >> 3;
  const int scol = (((tid & 7) ^ ((tid >> 3) & 7)) << 3);

  const _Float16* gA = A + (size_t)blockIdx.z * sAz + (size_t)(bm0 + srow) * lda + scol;
  const _Float16* gB = B + (size_t)blockIdx.z * sBz + (size_t)(bn0 + srow) * ldb + scol;

  const int NT = K >> 6, NI = K >> 7;

  f32x4 acc[8][4] = {};
  half8 aA[4][2], bs0[2][2], bs1[2][2];

  // prologue: tile0 full (buf0) + tile1 h0s (buf1); vmcnt(4) retires tile0
  STAGEA(0, 0, 0); STAGEA(0, 1, 0); STAGEB(0, 0, 0); STAGEB(0, 1, 0);
  STAGEA(1, 0, 1); STAGEB(1, 0, 1);
  __builtin_amdgcn_sched_barrier(0);
  asm volatile("s_waitcnt vmcnt(4)" ::: "memory");
  __builtin_amdgcn_s_barrier();
  __builtin_amdgcn_sched_barrier(0);

  for (int i = 0; i < NI; ++i) {
    const int t1 = 2 * i + 1;
    int t2c = 2 * i + 2; if (t2c > NT - 1) t2c = NT - 1;
    int t3c = 2 * i + 3; if (t3c > NT - 1) t3c = NT - 1;
    // Qa(2i) [buf0]: stage h1s of tile 2i+1 -> buf1
    STAGEA(t1, 1, 1); STAGEB(t1, 1, 1);
    LOADA_TO(aA, 0, 0) LOADB_TO(bs0, 0, 0) LOADB_TO(bs1, 1, 0)
    SYNC_PRE DO_MFMA2(aA, bs0, 0, 0) DO_MFMA2(aA, bs1, 0, 1) SYNC_POST
    // Qb(2i): stage h0s of tile 2i+2 -> buf0 ; vmcnt(4): tile 2i+1 ready
    STAGEA(t2c, 0, 0); STAGEB(t2c, 0, 0);
    LOADA_TO(aA, 1, 0)
    SYNC_PRE DO_MFMA2(aA, bs0, 1, 0) DO_MFMA2(aA, bs1, 1, 1) SYNC_POST_VM
    // Qa(2i+1) [buf1]: stage h1s of tile 2i+2 -> buf0
    STAGEA(t2c, 1, 0); STAGEB(t2c, 1, 0);
    LOADA_TO(aA, 0, 1) LOADB_TO(bs0, 0, 1) LOADB_TO(bs1, 1, 1)
    SYNC_PRE DO_MFMA2(aA, bs0, 0, 0) DO_MFMA2(aA, bs1, 0, 1) SYNC_POST
    // Qb(2i+1): stage h0s of tile 2i+3 -> buf1 ; vmcnt(4): tile 2i+2 ready
    STAGEA(t3c, 0, 1); STAGEB(t3c, 0, 1);
    LOADA_TO(aA, 1, 1)
    SYNC_PRE DO_MFMA2(aA, bs0, 1, 0) DO_MFMA2(aA, bs1, 1, 1) SYNC_POST_VM
  }

  if constexpr (EPI == 0) {
    float* Cb = (float*)Cv + (size_t)blockIdx.z * sCz;
#pragma unroll
    for (int m = 0; m < 8; ++m) {
      int row0 = bm0 + m * 32 + wr * 16 + lhi * 4;
#pragma unroll
      for (int n = 0; n < 4; ++n) {
        int col = bn0 + n * 64 + wcn * 16 + l16;
#pragma unroll
        for (int v = 0; v < 4; ++v)
          Cb[(size_t)(row0 + v) * ldc + col] = acc[m][n][v];
      }
    }
  } else if constexpr (EPI == 1) {
    _Float16* Cb = (_Float16*)Cv;
#pragma unroll
    for (int n = 0; n < 4; ++n) {
      int col = bn0 + n * 64 + wcn * 16 + l16;
      float bv = bias[col];
#pragma unroll
      for (int m = 0; m < 8; ++m) {
        int row0 = bm0 + m * 32 + wr * 16 + lhi * 4;
        Cb[(size_t)(row0 + 0) * ldc + col] = (_Float16)fmaxf(acc[m][n][0] + bv, 0.f);
        Cb[(size_t)(row0 + 1) * ldc + col] = (_Float16)fmaxf(acc[m][n][1] + bv, 0.f);
        Cb[(size_t)(row0 + 2) * ldc + col] = (_Float16)fmaxf(acc[m][n][2] + bv, 0.f);
        Cb[(size_t)(row0 + 3) * ldc + col] = (_Float16)fmaxf(acc[m][n][3] + bv, 0.f);
      }
    }
  } else {
    // EPI == 2: partial softmax over this block's 256 cols.
    // redm/reds in smem[0,8KB): final outstanding GLPs target buf1-h0 only;
    // __syncthreads() drains counters before first use.
    float* redm = (float*)smW;            // [256][4]
    float* reds = (float*)(smW + 4096);   // [256][4]
    float tm[8][4];
#pragma unroll
    for (int m = 0; m < 8; ++m)
#pragma unroll
      for (int v = 0; v < 4; ++v)
        tm[m][v] = fmaxf(fmaxf(acc[m][0][v], acc[m][1][v]),
                         fmaxf(acc[m][2][v], acc[m][3][v]));
#pragma unroll
    for (int o = 1; o < 16; o <<= 1)
#pragma unroll
      for (int m = 0; m < 8; ++m)
#pragma unroll
        for (int v = 0; v < 4; ++v)
          tm[m][v] = fmaxf(tm[m][v], __shfl_xor(tm[m][v], o));
    __syncthreads();
    if (l16 == 0) {
#pragma unroll
      for (int m = 0; m < 8; ++m)
#pragma unroll
        for (int v = 0; v < 4; ++v)
          redm[(m * 32 + wr * 16 + lhi * 4 + v) * 4 + wcn] = tm[m][v];
    }
    __syncthreads();
    float rm[8][4], rs[8][4];
#pragma unroll
    for (int m = 0; m < 8; ++m)
#pragma unroll
      for (int v = 0; v < 4; ++v) {
        float4 q4 = ((const float4*)redm)[m * 32 + wr * 16 + lhi * 4 + v];
        rm[m][v] = fmaxf(fmaxf(q4.x, q4.y), fmaxf(q4.z, q4.w));
      }
#pragma unroll
    for (int m = 0; m < 8; ++m)
#pragma unroll
      for (int v = 0; v < 4; ++v) {
        float s = 0.f;
#pragma unroll
        for (int n = 0; n < 4; ++n) {
          float e = __expf(acc[m][n][v] - rm[m][v]);
          acc[m][n][v] = e;
          s += e;
        }
        tm[m][v] = s;
      }
#pragma unroll
    for (int o = 1; o < 16; o <<= 1)
#pragma unroll
      for (int m = 0; m < 8; ++m)
#pragma unroll
        for (int v = 0; v < 4; ++v)
          tm[m][v] += __shfl_xor(tm[m][v], o);
    __syncthreads();
    if (l16 == 0) {
#pragma unroll
      for (int m = 0; m < 8; ++m)
#pragma unroll
        for (int v = 0; v < 4; ++v)
          reds[(m * 32 + wr * 16 + lhi * 4 + v) * 4 + wcn] = tm[m][v];
    }
    __syncthreads();
#pragma unroll
    for (int m = 0; m < 8; ++m)
#pragma unroll
      for (int v = 0; v < 4; ++v) {
        float4 q4 = ((const float4*)reds)[m * 32 + wr * 16 + lhi * 4 + v];
        rs[m][v] = (q4.x + q4.y) + (q4.z + q4.w);
      }
    _Float16* Cb = (_Float16*)Cv + (size_t)blockIdx.z * sCz;
#pragma unroll
    for (int n = 0; n < 4; ++n) {
      int col = bn0 + n * 64 + wcn * 16 + l16;
#pragma unroll
      for (int m = 0; m < 8; ++m) {
        int row0 = bm0 + m * 32 + wr * 16 + lhi * 4;
        Cb[(size_t)(row0 + 0) * ldc + col] = (_Float16)acc[m][n][0];
        Cb[(size_t)(row0 + 1) * ldc + col] = (_Float16)acc[m][n][1];
        Cb[(size_t)(row0 + 2) * ldc + col] = (_Float16)acc[m][n][2];
        Cb[(size_t)(row0 + 3) * ldc + col] = (_Float16)acc[m][n][3];
      }
    }
    if (l16 == 0 && wcn == 0) {
      float2* sb = side + ((size_t)blockIdx.z * 2048 + bm0) * 8 + (bn0 >> 8);
#pragma unroll
      for (int m = 0; m < 8; ++m)
#pragma unroll
        for (int v = 0; v < 4; ++v) {
          int r = m * 32 + wr * 16 + lhi * 4 + v;
          sb[(size_t)r * 8] = make_float2(rm[m][v], rs[m][v]);
        }
    }
  }
}

// ---------------------------------------------------------------- global renorm
__global__ __launch_bounds__(256) void renorm_k(_Float16* __restrict__ P,
                                                const float2* __restrict__ side) {
  const int row = blockIdx.x;
  const int bz = blockIdx.y;
  const float2* sd = side + ((size_t)bz * 2048 + row) * 8;
  float mt[8], st[8];
#pragma unroll
  for (int t = 0; t < 8; ++t) { float2 v = sd[t]; mt[t] = v.x; st[t] = v.y; }
  float m = mt[0];
#pragma unroll
  for (int t = 1; t < 8; ++t) m = fmaxf(m, mt[t]);
  float S = 0.f;
#pragma unroll
  for (int t = 0; t < 8; ++t) S += st[t] * __expf(mt[t] - m);
  const float inv = 1.f / S;
  const int tid = threadIdx.x;
  const float sc = __expf(mt[tid >> 5] - m) * inv;
  _Float16* p = P + (((size_t)bz * 2048 + row) * 2048) + tid * 8;
  half8 v = *(half8*)p;
#pragma unroll
  for (int j = 0; j < 8; ++j) v[j] = (_Float16)((float)v[j] * sc);
  *(half8*)p = v;
}

// ---------------------------------------------------------------- launch
extern "C" void kernel_launch(void* const* d_in, const int* in_sizes, int n_in,
                              void* d_out, int out_size, void* d_ws, size_t ws_size,
                              hipStream_t stream) {
  const float* q = (const float*)d_in[0];
  const float* p = (const float*)d_in[1];
  const float* W = (const float*)d_in[2];
  const float* bias = (const float*)d_in[3];
  float* out = (float*)d_out;
  char* ws = (char*)d_ws;

  _Float16* qf    = (_Float16*)(ws);
  _Float16* pf    = (_Float16*)(ws + 67108864L);
  _Float16* qlin  = (_Float16*)(ws + 134217728L);
  _Float16* plin  = (_Float16*)(ws + 201326592L);
  _Float16* qlinT = (_Float16*)(ws + 268435456L);
  _Float16* Wf    = (_Float16*)(ws + 335544320L);
  _Float16* Pbuf  = (_Float16*)(ws);
  float2*   side  = (float2*)(ws + 67108864L);

  const long nQ = (long)NBATCH * LQN * HD;
  const size_t SH = 131072;

  cvt_f32_f16<<<2048, 256, 0, stream>>>(q, qf, nQ / 4);
  cvt_f32_f16<<<2048, 256, 0, stream>>>(p, pf, nQ / 4);
  cvt_f32_f16<<<64, 256, 0, stream>>>(W, Wf, (long)HD * HD / 4);

  gemm8p<1><<<dim3(HD / 256, 2 * NBATCH * LQN / 256, 1), 512, SH, stream>>>(
      qf, Wf, bias, qlin, (float2*)0, HD, HD, HD, HD, 0, 0, 0);

  transpose_k<<<dim3(LQN / 64, HD / 64, NBATCH), 256, 0, stream>>>(qlin, qlinT);

  for (int c = 0; c < 2; ++c) {
    int bz0 = c * 8;
    gemm8p<2><<<dim3(LQN / 256, LPN / 256, 8), 512, SH, stream>>>(
        plin + (size_t)bz0 * LPN * HD, qlin + (size_t)bz0 * LQN * HD,
        (const float*)0, Pbuf, side,
        /*K=*/HD, /*lda=*/HD, /*ldb=*/HD, /*ldc=*/LQN,
        (long)LPN * HD, (long)LQN * HD, (long)LPN * LQN);
    renorm_k<<<dim3(LPN, 8), 256, 0, stream>>>(Pbuf, side);
    gemm8p<0><<<dim3(HD / 256, LPN / 256, 8), 512, SH, stream>>>(
        Pbuf, qlinT + (size_t)bz0 * HD * LQN,
        (const float*)0, out + (size_t)bz0 * LPN * HD, (float2*)0,
        /*K=*/LQN, /*lda=*/LQN, /*ldb=*/LQN, /*ldc=*/HD,
        (long)LPN * LQN, (long)HD * LQN, (long)LPN * HD);
  }
}